// Round 4
// baseline (132.330 us; speedup 1.0000x reference)
//
#include <hip/hip_runtime.h>
#include <hip/hip_bf16.h>

#define B_N 64
#define D_IN 12288      // K*G*G
#define HG0 512
#define OUT_N 1024      // HG0+HL

// GEMM1: grid (32 j-tiles, KC1 kc); block = 4 waves, each wave covers DWAVE1 d
#define KC1 32
#define DBLOCK1 384     // per block (4 waves x 96)
#define DWAVE1 96       // 3 k-steps of 32

#define NFOV 3072       // foveate blocks (64*12288/256)
#define NW34 512        // W34 conversion blocks (1024*512/1024)

typedef __attribute__((ext_vector_type(8))) short bf16x8;
typedef __attribute__((ext_vector_type(4))) float f32x4;

static __device__ __forceinline__ short f2bf(float f) {
  __hip_bfloat16 h = __float2bfloat16(f);
  return *reinterpret_cast<short*>(&h);
}

// ---------- Kernel 1: foveate -> phi_bf16[b][12288]  +  w34 = bf16(W3+W4) + zero counters ----------
__global__ __launch_bounds__(256) void prep_kernel(
    const float* __restrict__ x, const float* __restrict__ l,
    const float* __restrict__ W3, const float* __restrict__ W4,
    short* __restrict__ phi, short* __restrict__ w34, int* __restrict__ cnt) {
  int bx = blockIdx.x;
  if (bx >= NFOV) {
    // W34 part: each block converts 1024 floats (256 threads x float4)
    int e = (bx - NFOV) * 1024 + threadIdx.x * 4;
    float4 a = *(const float4*)(W3 + e);
    float4 b = *(const float4*)(W4 + e);
    short4 o;
    o.x = f2bf(a.x + b.x); o.y = f2bf(a.y + b.y);
    o.z = f2bf(a.z + b.z); o.w = f2bf(a.w + b.w);
    *(short4*)(w34 + e) = o;
    if (bx == NFOV && threadIdx.x < 32) cnt[threadIdx.x] = 0;
    return;
  }

  int idx = bx * 256 + threadIdx.x;   // b*D_IN + d
  int b = idx / D_IN;
  int d = idx - b * D_IN;
  int k = d >> 12;
  int rem = d & 4095;
  int gy = rem >> 6, gx = rem & 63;

  float lx = l[b * 2 + 0];
  float ly = l[b * 2 + 1];
  int cx = (int)(0.5f * ((lx + 1.0f) * 1024.0f));   // trunc, matches .astype(int32)
  int cy = (int)(0.5f * ((ly + 1.0f) * 1024.0f));

  const float* xb = x + ((size_t)b << 20);
  float v;

  if (k == 0) {          // r=4, half=128
    int y0 = cy - 128 + gy * 4;
    int x0 = cx - 128 + gx * 4;
    float s = 0.0f;
    #pragma unroll
    for (int dy = 0; dy < 4; ++dy) {
      int yy = y0 + dy;
      if ((unsigned)yy < 1024u) {
        const float* row = xb + ((size_t)yy << 10);
        #pragma unroll
        for (int dx = 0; dx < 4; ++dx) {
          int xx = x0 + dx;
          if ((unsigned)xx < 1024u) s += row[xx];
        }
      }
    }
    v = s * 0.0625f;
  } else if (k == 1) {   // r=2, half=64
    int y0 = cy - 64 + gy * 2;
    int x0 = cx - 64 + gx * 2;
    float s = 0.0f;
    #pragma unroll
    for (int dy = 0; dy < 2; ++dy) {
      int yy = y0 + dy;
      if ((unsigned)yy < 1024u) {
        const float* row = xb + ((size_t)yy << 10);
        #pragma unroll
        for (int dx = 0; dx < 2; ++dx) {
          int xx = x0 + dx;
          if ((unsigned)xx < 1024u) s += row[xx];
        }
      }
    }
    v = s * 0.25f;
  } else {               // r=1, half=32
    int yy = cy - 32 + gy;
    int xx = cx - 32 + gx;
    v = 0.0f;
    if ((unsigned)yy < 1024u && (unsigned)xx < 1024u) v = xb[((size_t)yy << 10) + xx];
  }
  phi[idx] = f2bf(v);
}

// ---------- Kernel 2: GEMM1 (MFMA, split-K + deterministic last-block reduce) ----------
// C[j][b] = sum_d W1[j][d] * phi[b][d] ; last kc-block per j-tile reduces -> h_bf16[b][512]
__global__ __launch_bounds__(256) void gemm1_kernel(
    const short* __restrict__ phi, const float* __restrict__ W1,
    float* __restrict__ partial1, short* __restrict__ h, int* __restrict__ cnt) {
  __shared__ float lds[4 * 16 * 64];   // [wave][j_local][b] 16KB
  __shared__ int lastflag;
  int wave = threadIdx.x >> 6;
  int lane = threadIdx.x & 63;
  int lc = lane & 15;       // A row = j ; B col = b
  int kg = lane >> 4;
  int j0 = blockIdx.x * 16;
  int dbase = blockIdx.y * DBLOCK1 + wave * DWAVE1;

  f32x4 acc[4] = {{0,0,0,0},{0,0,0,0},{0,0,0,0},{0,0,0,0}};

  const float* wrow = W1 + (size_t)(j0 + lc) * D_IN + kg * 8;
  const short* prow = phi + kg * 8;

  #pragma unroll
  for (int ks = 0; ks < DWAVE1 / 32; ++ks) {
    int d0 = dbase + ks * 32;
    float4 wa = *(const float4*)(wrow + d0);
    float4 wb = *(const float4*)(wrow + d0 + 4);
    bf16x8 af;
    af[0] = f2bf(wa.x); af[1] = f2bf(wa.y); af[2] = f2bf(wa.z); af[3] = f2bf(wa.w);
    af[4] = f2bf(wb.x); af[5] = f2bf(wb.y); af[6] = f2bf(wb.z); af[7] = f2bf(wb.w);
    #pragma unroll
    for (int t = 0; t < 4; ++t) {
      bf16x8 bf = *(const bf16x8*)(prow + (size_t)(t * 16 + lc) * D_IN + d0);
      acc[t] = __builtin_amdgcn_mfma_f32_16x16x32_bf16(af, bf, acc[t], 0, 0, 0);
    }
  }

  // stash per-wave results: lds[w][j_local = kg*4+r][b = t*16+lc]
  #pragma unroll
  for (int t = 0; t < 4; ++t)
    #pragma unroll
    for (int r = 0; r < 4; ++r)
      lds[wave * 1024 + (kg * 4 + r) * 64 + t * 16 + lc] = acc[t][r];
  __syncthreads();

  // reduce 4 waves -> partial1[kc][j0*64 + e]  (coalesced)
  float* pp = partial1 + (size_t)blockIdx.y * (HG0 * 64) + (size_t)j0 * 64;
  #pragma unroll
  for (int i = 0; i < 4; ++i) {
    int e = threadIdx.x + 256 * i;
    pp[e] = lds[e] + lds[1024 + e] + lds[2048 + e] + lds[3072 + e];
  }

  // ---- deterministic split-K completion: last kc-block for this j-tile reduces ----
  __threadfence();                       // release my partial stores to device scope
  __syncthreads();
  if (threadIdx.x == 0) {
    int t = atomicAdd(&cnt[blockIdx.x], 1);
    lastflag = (t == KC1 - 1);
  }
  __syncthreads();
  if (!lastflag) return;
  __threadfence();                       // acquire: see all blocks' partials

  const float* pbase = partial1 + (size_t)j0 * 64;
  #pragma unroll
  for (int i = 0; i < 4; ++i) {
    int e = threadIdx.x + 256 * i;
    float s = 0.0f;
    #pragma unroll
    for (int kc = 0; kc < KC1; ++kc) s += pbase[(size_t)kc * (HG0 * 64) + e];
    float v = (s >= 0.0f) ? s : 0.01f * s;
    int j = j0 + (e >> 6), b = e & 63;
    h[(size_t)b * HG0 + j] = f2bf(v);
  }
}

// ---------- Kernel 3: GEMM2 fused (MFMA + block split-K + lrelu) ----------
// out[b][o] = lrelu( sum_j h[b][j] * w34[o][j] )
__global__ __launch_bounds__(256) void gemm2_kernel(
    const short* __restrict__ h, const short* __restrict__ w34,
    float* __restrict__ out) {
  __shared__ float lds[4 * 1024];   // 16KB
  int wave = threadIdx.x >> 6;
  int lane = threadIdx.x & 63;
  int lc = lane & 15;       // B col = o ; A row = b
  int kg = lane >> 4;
  int o0 = blockIdx.x * 16;
  int jbase = wave * 128;

  f32x4 acc[4] = {{0,0,0,0},{0,0,0,0},{0,0,0,0},{0,0,0,0}};

  #pragma unroll
  for (int ks = 0; ks < 4; ++ks) {
    int j0 = jbase + ks * 32;
    bf16x8 bf = *(const bf16x8*)(w34 + (size_t)(o0 + lc) * HG0 + j0 + kg * 8);
    #pragma unroll
    for (int t = 0; t < 4; ++t) {
      bf16x8 af = *(const bf16x8*)(h + (size_t)(t * 16 + lc) * HG0 + j0 + kg * 8);
      acc[t] = __builtin_amdgcn_mfma_f32_16x16x32_bf16(af, bf, acc[t], 0, 0, 0);
    }
  }

  // acc[t][r] = C[b = t*16 + kg*4 + r][o = o0 + lc]
  #pragma unroll
  for (int t = 0; t < 4; ++t)
    #pragma unroll
    for (int r = 0; r < 4; ++r)
      lds[wave * 1024 + t * 256 + kg * 64 + r * 16 + lc] = acc[t][r];
  __syncthreads();

  #pragma unroll
  for (int i = 0; i < 4; ++i) {
    int e = threadIdx.x + 256 * i;
    float s = lds[e] + lds[1024 + e] + lds[2048 + e] + lds[3072 + e];
    float v = (s >= 0.0f) ? s : 0.01f * s;
    int b = ((e >> 8) << 4) + (((e >> 6) & 3) << 2) + ((e >> 4) & 3);
    out[(size_t)b * OUT_N + o0 + (e & 15)] = v;
  }
}

extern "C" void kernel_launch(void* const* d_in, const int* in_sizes, int n_in,
                              void* d_out, int out_size, void* d_ws, size_t ws_size,
                              hipStream_t stream) {
  const float* x  = (const float*)d_in[0];
  const float* l  = (const float*)d_in[1];
  const float* W1 = (const float*)d_in[2];
  const float* W3 = (const float*)d_in[4];
  const float* W4 = (const float*)d_in[5];
  float* out = (float*)d_out;

  char* ws = (char*)d_ws;
  short* phi      = (short*)(ws);                  // 64*12288*2   = 1.5 MB
  float* partial1 = (float*)(ws + (2u << 20));     // 32*512*64*4  = 4 MB
  short* h        = (short*)(ws + (6u << 20));     // 64*512*2     = 64 KB
  short* w34      = (short*)(ws + (7u << 20));     // 1024*512*2   = 1 MB
  int*   cnt      = (int*)(ws + (9u << 20));       // 32 ints

  prep_kernel<<<dim3(NFOV + NW34), dim3(256), 0, stream>>>(x, l, W3, W4, phi, w34, cnt);
  gemm1_kernel<<<dim3(32, KC1), dim3(256), 0, stream>>>(phi, W1, partial1, h, cnt);
  gemm2_kernel<<<dim3(OUT_N / 16), dim3(256), 0, stream>>>(h, w34, out);
}

// Round 5
// 33.190 us; speedup vs baseline: 3.9870x; 3.9870x over previous
//
#include <hip/hip_runtime.h>
#include <hip/hip_bf16.h>

#define B_N 64
#define D_IN 12288      // K*G*G
#define HG0 512
#define OUT_N 1024      // HG0+HL

// GEMM1: grid (32 j-tiles, KC1 kc); block = 8 waves, each wave covers DWAVE1 d
#define KC1 16
#define DBLOCK1 768     // per block (8 waves x 96)
#define DWAVE1 96       // 3 k-steps of 32

#define NFOV 3072       // foveate blocks (64*12288/256)
#define NW34 512        // W34 conversion blocks (1024*512/1024)

typedef __attribute__((ext_vector_type(8))) short bf16x8;
typedef __attribute__((ext_vector_type(4))) float f32x4;

static __device__ __forceinline__ short f2bf(float f) {
  __hip_bfloat16 h = __float2bfloat16(f);
  return *reinterpret_cast<short*>(&h);
}

// ---------- Kernel 1: foveate -> phi_bf16[b][12288]  +  w34 = bf16(W3+W4) ----------
__global__ __launch_bounds__(256) void prep_kernel(
    const float* __restrict__ x, const float* __restrict__ l,
    const float* __restrict__ W3, const float* __restrict__ W4,
    short* __restrict__ phi, short* __restrict__ w34) {
  int bx = blockIdx.x;
  if (bx >= NFOV) {
    // W34 part: each block converts 1024 floats (256 threads x float4)
    int e = (bx - NFOV) * 1024 + threadIdx.x * 4;
    float4 a = *(const float4*)(W3 + e);
    float4 b = *(const float4*)(W4 + e);
    short4 o;
    o.x = f2bf(a.x + b.x); o.y = f2bf(a.y + b.y);
    o.z = f2bf(a.z + b.z); o.w = f2bf(a.w + b.w);
    *(short4*)(w34 + e) = o;
    return;
  }

  int idx = bx * 256 + threadIdx.x;   // b*D_IN + d
  int b = idx / D_IN;
  int d = idx - b * D_IN;
  int k = d >> 12;
  int rem = d & 4095;
  int gy = rem >> 6, gx = rem & 63;

  float lx = l[b * 2 + 0];
  float ly = l[b * 2 + 1];
  int cx = (int)(0.5f * ((lx + 1.0f) * 1024.0f));   // trunc, matches .astype(int32)
  int cy = (int)(0.5f * ((ly + 1.0f) * 1024.0f));

  const float* xb = x + ((size_t)b << 20);
  float v;

  if (k == 0) {          // r=4, half=128
    int y0 = cy - 128 + gy * 4;
    int x0 = cx - 128 + gx * 4;
    float s = 0.0f;
    #pragma unroll
    for (int dy = 0; dy < 4; ++dy) {
      int yy = y0 + dy;
      if ((unsigned)yy < 1024u) {
        const float* row = xb + ((size_t)yy << 10);
        #pragma unroll
        for (int dx = 0; dx < 4; ++dx) {
          int xx = x0 + dx;
          if ((unsigned)xx < 1024u) s += row[xx];
        }
      }
    }
    v = s * 0.0625f;
  } else if (k == 1) {   // r=2, half=64
    int y0 = cy - 64 + gy * 2;
    int x0 = cx - 64 + gx * 2;
    float s = 0.0f;
    #pragma unroll
    for (int dy = 0; dy < 2; ++dy) {
      int yy = y0 + dy;
      if ((unsigned)yy < 1024u) {
        const float* row = xb + ((size_t)yy << 10);
        #pragma unroll
        for (int dx = 0; dx < 2; ++dx) {
          int xx = x0 + dx;
          if ((unsigned)xx < 1024u) s += row[xx];
        }
      }
    }
    v = s * 0.25f;
  } else {               // r=1, half=32
    int yy = cy - 32 + gy;
    int xx = cx - 32 + gx;
    v = 0.0f;
    if ((unsigned)yy < 1024u && (unsigned)xx < 1024u) v = xb[((size_t)yy << 10) + xx];
  }
  phi[idx] = f2bf(v);
}

// ---------- Kernel 2: GEMM1 (MFMA, block split-K over 8 waves): partial1[kc][j*64+b] ----------
// C[j][b] = sum_d W1[j][d] * phi[b][d]
// grid (32, KC1), block 512: wave w covers d-chunk blockIdx.y*768 + w*96
__global__ __launch_bounds__(512) void gemm1_kernel(
    const short* __restrict__ phi, const float* __restrict__ W1,
    float* __restrict__ partial1) {
  __shared__ float lds[8 * 16 * 64];   // [wave][j_local][b] 32KB
  int wave = threadIdx.x >> 6;
  int lane = threadIdx.x & 63;
  int lc = lane & 15;       // A row = j ; B col = b
  int kg = lane >> 4;
  int j0 = blockIdx.x * 16;
  int dbase = blockIdx.y * DBLOCK1 + wave * DWAVE1;

  f32x4 acc[4] = {{0,0,0,0},{0,0,0,0},{0,0,0,0},{0,0,0,0}};

  const float* wrow = W1 + (size_t)(j0 + lc) * D_IN + kg * 8;
  const short* prow = phi + kg * 8;

  #pragma unroll
  for (int ks = 0; ks < DWAVE1 / 32; ++ks) {
    int d0 = dbase + ks * 32;
    float4 wa = *(const float4*)(wrow + d0);
    float4 wb = *(const float4*)(wrow + d0 + 4);
    bf16x8 af;
    af[0] = f2bf(wa.x); af[1] = f2bf(wa.y); af[2] = f2bf(wa.z); af[3] = f2bf(wa.w);
    af[4] = f2bf(wb.x); af[5] = f2bf(wb.y); af[6] = f2bf(wb.z); af[7] = f2bf(wb.w);
    #pragma unroll
    for (int t = 0; t < 4; ++t) {
      bf16x8 bf = *(const bf16x8*)(prow + (size_t)(t * 16 + lc) * D_IN + d0);
      acc[t] = __builtin_amdgcn_mfma_f32_16x16x32_bf16(af, bf, acc[t], 0, 0, 0);
    }
  }

  // stash per-wave results: lds[w][j_local = kg*4+r][b = t*16+lc]
  #pragma unroll
  for (int t = 0; t < 4; ++t)
    #pragma unroll
    for (int r = 0; r < 4; ++r)
      lds[wave * 1024 + (kg * 4 + r) * 64 + t * 16 + lc] = acc[t][r];
  __syncthreads();

  // reduce 8 waves -> partial1[kc][j0*64 + e]  (coalesced)
  float* pp = partial1 + (size_t)blockIdx.y * (HG0 * 64) + (size_t)j0 * 64;
  #pragma unroll
  for (int i = 0; i < 2; ++i) {
    int e = threadIdx.x + 512 * i;
    float s = 0.0f;
    #pragma unroll
    for (int w = 0; w < 8; ++w) s += lds[w * 1024 + e];
    pp[e] = s;
  }
}

// ---------- Kernel 3: reduce split-K + leaky -> h_bf16[b][512] ----------
__global__ __launch_bounds__(256) void reduce1_kernel(
    const float* __restrict__ partial1, short* __restrict__ h) {
  int idx = blockIdx.x * 256 + threadIdx.x;   // j*64 + b
  float s = 0.0f;
  #pragma unroll
  for (int kc = 0; kc < KC1; ++kc) s += partial1[(size_t)kc * (HG0 * 64) + idx];
  float v = (s >= 0.0f) ? s : 0.01f * s;
  int j = idx >> 6, b = idx & 63;
  h[(size_t)b * HG0 + j] = f2bf(v);
}

// ---------- Kernel 4: GEMM2 fused (MFMA + block split-K + lrelu) ----------
// out[b][o] = lrelu( sum_j h[b][j] * w34[o][j] )
__global__ __launch_bounds__(256) void gemm2_kernel(
    const short* __restrict__ h, const short* __restrict__ w34,
    float* __restrict__ out) {
  __shared__ float lds[4 * 1024];   // 16KB
  int wave = threadIdx.x >> 6;
  int lane = threadIdx.x & 63;
  int lc = lane & 15;       // B col = o ; A row = b
  int kg = lane >> 4;
  int o0 = blockIdx.x * 16;
  int jbase = wave * 128;

  f32x4 acc[4] = {{0,0,0,0},{0,0,0,0},{0,0,0,0},{0,0,0,0}};

  #pragma unroll
  for (int ks = 0; ks < 4; ++ks) {
    int j0 = jbase + ks * 32;
    bf16x8 bf = *(const bf16x8*)(w34 + (size_t)(o0 + lc) * HG0 + j0 + kg * 8);
    #pragma unroll
    for (int t = 0; t < 4; ++t) {
      bf16x8 af = *(const bf16x8*)(h + (size_t)(t * 16 + lc) * HG0 + j0 + kg * 8);
      acc[t] = __builtin_amdgcn_mfma_f32_16x16x32_bf16(af, bf, acc[t], 0, 0, 0);
    }
  }

  // acc[t][r] = C[b = t*16 + kg*4 + r][o = o0 + lc]
  #pragma unroll
  for (int t = 0; t < 4; ++t)
    #pragma unroll
    for (int r = 0; r < 4; ++r)
      lds[wave * 1024 + t * 256 + kg * 64 + r * 16 + lc] = acc[t][r];
  __syncthreads();

  #pragma unroll
  for (int i = 0; i < 4; ++i) {
    int e = threadIdx.x + 256 * i;
    float s = lds[e] + lds[1024 + e] + lds[2048 + e] + lds[3072 + e];
    float v = (s >= 0.0f) ? s : 0.01f * s;
    int b = ((e >> 8) << 4) + (((e >> 6) & 3) << 2) + ((e >> 4) & 3);
    out[(size_t)b * OUT_N + o0 + (e & 15)] = v;
  }
}

extern "C" void kernel_launch(void* const* d_in, const int* in_sizes, int n_in,
                              void* d_out, int out_size, void* d_ws, size_t ws_size,
                              hipStream_t stream) {
  const float* x  = (const float*)d_in[0];
  const float* l  = (const float*)d_in[1];
  const float* W1 = (const float*)d_in[2];
  const float* W3 = (const float*)d_in[4];
  const float* W4 = (const float*)d_in[5];
  float* out = (float*)d_out;

  char* ws = (char*)d_ws;
  short* phi      = (short*)(ws);                  // 64*12288*2   = 1.5 MB
  float* partial1 = (float*)(ws + (2u << 20));     // 16*512*64*4  = 2 MB
  short* h        = (short*)(ws + (6u << 20));     // 64*512*2     = 64 KB
  short* w34      = (short*)(ws + (7u << 20));     // 1024*512*2   = 1 MB

  prep_kernel<<<dim3(NFOV + NW34), dim3(256), 0, stream>>>(x, l, W3, W4, phi, w34);
  gemm1_kernel<<<dim3(32, KC1), dim3(512), 0, stream>>>(phi, W1, partial1);
  reduce1_kernel<<<dim3((HG0 * 64) / 256), dim3(256), 0, stream>>>(partial1, h);
  gemm2_kernel<<<dim3(OUT_N / 16), dim3(256), 0, stream>>>(h, w34, out);
}